// Round 1
// baseline (992.447 us; speedup 1.0000x reference)
//
#include <hip/hip_runtime.h>
#include <cmath>

#define BB 512
#define NN 2048
#define DD 128

// ---------------------------------------------------------------------------
// Kernel 1: per batch row b compute
//   Qp[e] = sum_d Q[b,d] * W1[e,d] + b1[e]
//   qt[b,d] = sum_e Qp[e] * W2[e,d]          (so alpha = K[b,n] . qt[b] + c)
//   c[b]  = sum_e Qp[e] * b2[e]
// ---------------------------------------------------------------------------
__global__ __launch_bounds__(128) void prep_kernel(
    const float* __restrict__ Q, const float* __restrict__ W1,
    const float* __restrict__ b1, const float* __restrict__ W2,
    const float* __restrict__ b2, float* __restrict__ qt,
    float* __restrict__ cvec) {
  const int b = blockIdx.x;
  const int t = threadIdx.x;  // 0..127
  __shared__ float Qs[DD];
  __shared__ float Qp[DD];
  __shared__ float red[DD];

  Qs[t] = Q[b * DD + t];
  __syncthreads();

  // Qp[t] = Q[b,:] . W1[t,:] + b1[t]
  float acc = b1[t];
  const float4* w1row = (const float4*)(W1 + t * DD);
  #pragma unroll 8
  for (int i = 0; i < DD / 4; ++i) {
    float4 w = w1row[i];
    acc += Qs[4 * i + 0] * w.x + Qs[4 * i + 1] * w.y +
           Qs[4 * i + 2] * w.z + Qs[4 * i + 3] * w.w;
  }
  Qp[t] = acc;
  __syncthreads();

  // qt[b,t] = sum_e Qp[e] * W2[e,t]   (coalesced over t)
  float acc2 = 0.f;
  for (int e = 0; e < DD; ++e) acc2 += Qp[e] * W2[e * DD + t];
  qt[b * DD + t] = acc2;

  // c[b] = sum_e Qp[e] * b2[e]
  red[t] = Qp[t] * b2[t];
  __syncthreads();
  for (int s = 64; s > 0; s >>= 1) {
    if (t < s) red[t] += red[t + s];
    __syncthreads();
  }
  if (t == 0) cvec[b] = red[0];
}

// ---------------------------------------------------------------------------
// Kernel 2: one block per b. 256 threads = 8 groups of 32 lanes.
// Phase B: alpha[n] = K[b,n].qt[b] + c[b] - (1-adj)*1e30   (float4 coalesced)
// Softmax over n in LDS, write attn_weight.
// Phase C: attn_sum[d] = sum_n w[n] * V[b,n,d]             (float4 coalesced)
// ---------------------------------------------------------------------------
__global__ __launch_bounds__(256) void attn_kernel(
    const float* __restrict__ K, const float* __restrict__ V,
    const float* __restrict__ adj, const float* __restrict__ qt,
    const float* __restrict__ cvec, float* __restrict__ out_w,
    float* __restrict__ out_s) {
  const int b = blockIdx.x;
  const int tid = threadIdx.x;
  const int sub = tid & 31;   // lane within 32-group
  const int grp = tid >> 5;   // 0..7

  __shared__ float alpha[NN];       // 8 KB
  __shared__ float redC[8 * DD];    // 4 KB
  __shared__ float wredM[4];
  __shared__ float wredS[4];

  const float4 qv = ((const float4*)(qt + (size_t)b * DD))[sub];
  const float cb = cvec[b];
  const float4* K4 = (const float4*)(K + (size_t)b * NN * DD);
  const float4* V4 = (const float4*)(V + (size_t)b * NN * DD);
  const float* adjb = adj + (size_t)b * NN;

  // ---- Phase B: logits ----
  for (int nb = grp * 4; nb < NN; nb += 32) {
    float4 k0 = K4[(nb + 0) * 32 + sub];
    float4 k1 = K4[(nb + 1) * 32 + sub];
    float4 k2 = K4[(nb + 2) * 32 + sub];
    float4 k3 = K4[(nb + 3) * 32 + sub];
    float p0 = k0.x * qv.x + k0.y * qv.y + k0.z * qv.z + k0.w * qv.w;
    float p1 = k1.x * qv.x + k1.y * qv.y + k1.z * qv.z + k1.w * qv.w;
    float p2 = k2.x * qv.x + k2.y * qv.y + k2.z * qv.z + k2.w * qv.w;
    float p3 = k3.x * qv.x + k3.y * qv.y + k3.z * qv.z + k3.w * qv.w;
    #pragma unroll
    for (int off = 16; off > 0; off >>= 1) {
      p0 += __shfl_xor(p0, off);
      p1 += __shfl_xor(p1, off);
      p2 += __shfl_xor(p2, off);
      p3 += __shfl_xor(p3, off);
    }
    if (sub == 0) {
      alpha[nb + 0] = p0 + cb - (1.0f - adjb[nb + 0]) * 1e30f;
      alpha[nb + 1] = p1 + cb - (1.0f - adjb[nb + 1]) * 1e30f;
      alpha[nb + 2] = p2 + cb - (1.0f - adjb[nb + 2]) * 1e30f;
      alpha[nb + 3] = p3 + cb - (1.0f - adjb[nb + 3]) * 1e30f;
    }
  }
  __syncthreads();

  // ---- Softmax over n (2048 values in LDS) ----
  float m = -INFINITY;
  for (int i = tid; i < NN; i += 256) m = fmaxf(m, alpha[i]);
  #pragma unroll
  for (int off = 32; off > 0; off >>= 1) m = fmaxf(m, __shfl_xor(m, off));
  if ((tid & 63) == 0) wredM[tid >> 6] = m;
  __syncthreads();
  m = fmaxf(fmaxf(wredM[0], wredM[1]), fmaxf(wredM[2], wredM[3]));

  float s = 0.f;
  for (int i = tid; i < NN; i += 256) {
    float p = __expf(alpha[i] - m);
    alpha[i] = p;
    s += p;
  }
  #pragma unroll
  for (int off = 32; off > 0; off >>= 1) s += __shfl_xor(s, off);
  if ((tid & 63) == 0) wredS[tid >> 6] = s;
  __syncthreads();
  s = wredS[0] + wredS[1] + wredS[2] + wredS[3];
  const float inv = 1.0f / s;

  for (int i = tid; i < NN; i += 256) {
    float w = alpha[i] * inv;
    alpha[i] = w;
    out_w[(size_t)b * NN + i] = w;
  }
  __syncthreads();

  // ---- Phase C: attn_sum = sum_n w[n] * V[b,n,:] ----
  float ax = 0.f, ay = 0.f, az = 0.f, aw = 0.f;
  for (int nb = grp * 4; nb < NN; nb += 32) {
    float w0 = alpha[nb + 0];
    float w1 = alpha[nb + 1];
    float w2 = alpha[nb + 2];
    float w3 = alpha[nb + 3];
    float4 v0 = V4[(nb + 0) * 32 + sub];
    float4 v1 = V4[(nb + 1) * 32 + sub];
    float4 v2 = V4[(nb + 2) * 32 + sub];
    float4 v3 = V4[(nb + 3) * 32 + sub];
    ax += w0 * v0.x + w1 * v1.x + w2 * v2.x + w3 * v3.x;
    ay += w0 * v0.y + w1 * v1.y + w2 * v2.y + w3 * v3.y;
    az += w0 * v0.z + w1 * v1.z + w2 * v2.z + w3 * v3.z;
    aw += w0 * v0.w + w1 * v1.w + w2 * v2.w + w3 * v3.w;
  }
  float4 accv;
  accv.x = ax; accv.y = ay; accv.z = az; accv.w = aw;
  ((float4*)redC)[grp * 32 + sub] = accv;  // redC[grp*128 + sub*4 ..]
  __syncthreads();
  if (tid < DD) {
    float ssum = 0.f;
    #pragma unroll
    for (int g = 0; g < 8; ++g) ssum += redC[g * DD + tid];
    out_s[(size_t)b * DD + tid] = ssum;
  }
}

extern "C" void kernel_launch(void* const* d_in, const int* in_sizes, int n_in,
                              void* d_out, int out_size, void* d_ws, size_t ws_size,
                              hipStream_t stream) {
  const float* Q   = (const float*)d_in[0];
  const float* K   = (const float*)d_in[1];
  const float* V   = (const float*)d_in[2];
  const float* adj = (const float*)d_in[3];
  // d_in[4] = s_mask (unused by forward)
  const float* W1  = (const float*)d_in[5];
  const float* b1  = (const float*)d_in[6];
  const float* W2  = (const float*)d_in[7];
  const float* b2  = (const float*)d_in[8];

  float* out_w = (float*)d_out;                  // (B,1,N) flat
  float* out_s = out_w + (size_t)BB * NN;        // (B,D)

  float* qt   = (float*)d_ws;                    // B*D floats
  float* cvec = qt + (size_t)BB * DD;            // B floats

  prep_kernel<<<BB, DD, 0, stream>>>(Q, W1, b1, W2, b2, qt, cvec);
  attn_kernel<<<BB, 256, 0, stream>>>(K, V, adj, qt, cvec, out_w, out_s);
}